// Round 10
// baseline (384.650 us; speedup 1.0000x reference)
//
#include <hip/hip_runtime.h>
#include <stdint.h>

// ---------- types ----------
typedef __bf16 bf16x8 __attribute__((ext_vector_type(8)));
typedef __bf16 bf16x2 __attribute__((ext_vector_type(2)));
typedef float  f32x4  __attribute__((ext_vector_type(4)));
typedef unsigned short u16x4 __attribute__((ext_vector_type(4)));
typedef unsigned short u16x8 __attribute__((ext_vector_type(8)));

#define DEVI __device__ __forceinline__

// problem constants
constexpr int Bc = 4, Hc = 16, Ss = 2048, Dd = 128;
constexpr int BH = Bc * Hc;          // 64 heads
constexpr int BM = 256;              // q-rows per workgroup (4 waves x 64), mt=4
constexpr int MT = 4;                // 16-row fragments per wave
constexpr int NPAIR = Ss / 32;       // 64 key-pairs (32 keys each; body = 16 keys)
// scale folds in log2(e): e^(qk/128) = 2^((qk*log2e)/128)
constexpr float SCALE = 1.44269504088896340736f / 128.0f;

// wave-private LDS: K dbuf 2x4 KiB + V 8 KiB = 16 KiB per wave
constexpr int WAVE_LDS = 16384;
constexpr int LDS_BYTES = 4 * WAVE_LDS;   // 65536 -> 2 blocks/CU (128 KiB of 160)

DEVI unsigned short f2bf_bits(float x) {
  unsigned u = __builtin_bit_cast(unsigned, x);
  u += 0x7fffu + ((u >> 16) & 1u);          // round-to-nearest-even
  return (unsigned short)(u >> 16);
}
DEVI __bf16 f2bf(float x) {
  unsigned short b = f2bf_bits(x);
  return __builtin_bit_cast(__bf16, b);
}
// pack two fp32 -> dword of 2 bf16 (compiler emits v_cvt_pk_bf16_f32)
DEVI unsigned pk2(float a, float b) {
  bf16x2 t; t[0] = (__bf16)a; t[1] = (__bf16)b;
  return __builtin_bit_cast(unsigned, t);
}
// hardware 2^x (v_exp_f32)
DEVI float exp2_hw(float x) { return __builtin_amdgcn_exp2f(x); }

// async global->LDS, 16B per lane; LDS dest = wave-uniform base + lane*16
DEVI void gload_lds16(const void* g, void* l) {
  __builtin_amdgcn_global_load_lds(
      (const __attribute__((address_space(1))) unsigned*)(uintptr_t)g,
      (__attribute__((address_space(3))) unsigned*)(unsigned)(uintptr_t)l,
      16, 0, 0);
}

// ---------------- fused pre-pass (unchanged, measured-good) ----------------
constexpr int LDT2 = 136;
__global__ void k_prep(const float* __restrict__ kin, __bf16* __restrict__ kout,
                       const float* __restrict__ v, __bf16* __restrict__ vt) {
  __shared__ __align__(16) unsigned short tile[64 * LDT2];
  const int bx = blockIdx.x;
  const int u = threadIdx.x;
  if (bx >= 2048) {
    constexpr int N4 = (BH * Ss * Dd) / 4;
    int i = (bx - 2048) * 256 + u;
    const int stride = 2048 * 256;
    #pragma unroll
    for (int it = 0; it < N4 / (2048 * 256); it++, i += stride) {
      float4 x = ((const float4*)kin)[i];
      ushort4 o;
      o.x = f2bf_bits(x.x); o.y = f2bf_bits(x.y);
      o.z = f2bf_bits(x.z); o.w = f2bf_bits(x.w);
      ((ushort4*)kout)[i] = o;
    }
    return;
  }
  const int bh = bx >> 5;
  const int s0 = (bx & 31) * 64;
  const float4* src = (const float4*)(v + ((size_t)bh * Ss + s0) * Dd);
  #pragma unroll
  for (int i = 0; i < 8; i++) {
    int f = i * 256 + u;
    int row = f >> 5;
    int c4 = (f & 31) << 2;
    float4 x = src[f];
    u16x4 o;
    o[0] = f2bf_bits(x.x); o[1] = f2bf_bits(x.y);
    o[2] = f2bf_bits(x.z); o[3] = f2bf_bits(x.w);
    *(u16x4*)&tile[row * LDT2 + c4] = o;
  }
  __syncthreads();
  const int so = u & 7;
  const int dq = u >> 3;
  u16x4 tin[8];
  #pragma unroll
  for (int i = 0; i < 8; i++)
    tin[i] = *(const u16x4*)&tile[(so * 8 + i) * LDT2 + dq * 4];
  #pragma unroll
  for (int j = 0; j < 4; j++) {
    u16x8 o;
    #pragma unroll
    for (int i = 0; i < 8; i++) o[i] = tin[i][j];
    *(u16x8*)(vt + ((size_t)bh * Dd + dq * 4 + j) * Ss + s0 + so * 8) = o;
  }
}

// ---------------- flash attention: BARRIER-FREE ----------------
// grid: 512 = 8 q-tiles x 64 heads. Each wave is fully self-contained: it
// stages its own K/V into a private 16 KiB LDS slice with gload_lds + counted
// vmcnt (producer == consumer -> NO __syncthreads anywhere). Waves free-run
// and desync, overlapping one wave's exp burst with another's MFMA.
// Body = 16 keys; PV runs per PAIR of bodies at full K=32. Body-parity key
// permutation: body (p,par) stages key 32p + 8*quad' + 4*par + r at S^T slot
// (quad',r), so lane (quad,l16)'s exp'd scores across the pair are exactly
// P[q=l16][key=8*quad+j], j=4*par+r -- the K=32 PV A-fragment, lane-local.
__launch_bounds__(256, 2)
__global__ void k_flash(const float* __restrict__ Q, const __bf16* __restrict__ Kb,
                        const __bf16* __restrict__ Vt, float* __restrict__ O) {
  __shared__ __align__(16) char lds[LDS_BYTES];

  const int tid = threadIdx.x;
  const int w = tid >> 6;           // wave 0..3, owns q-rows [64w, 64w+64)
  const int lane = tid & 63;
  const int quad = lane >> 4;
  const int l16 = lane & 15;

  char* wlds = lds + w * WAVE_LDS;  // wave-private slice
  char* KB0 = wlds;                 // K buf for even bodies (par 0), 4 KiB
  char* KB1 = wlds + 4096;          // K buf for odd bodies (par 1), 4 KiB
  char* VB  = wlds + 8192;          // V buf for current pair, 8 KiB

  const int bx = blockIdx.x;
  const int bh = bx & (BH - 1);
  const int q0 = (bx >> 6) * BM;

  // ---- Q fragments: fp32 load, scale, cvt to bf16, keep in regs ----
  bf16x8 qa[MT][4];
  {
    const float* qb = Q + ((size_t)bh * Ss + q0 + w * 64) * Dd;
    #pragma unroll
    for (int mt = 0; mt < MT; mt++)
      #pragma unroll
      for (int kk = 0; kk < 4; kk++) {
        const float* p = qb + (mt * 16 + l16) * Dd + kk * 32 + quad * 8;
        float4 a = ((const float4*)p)[0];
        float4 b = ((const float4*)p)[1];
        bf16x8 f;
        f[0] = f2bf(a.x * SCALE); f[1] = f2bf(a.y * SCALE);
        f[2] = f2bf(a.z * SCALE); f[3] = f2bf(a.w * SCALE);
        f[4] = f2bf(b.x * SCALE); f[5] = f2bf(b.y * SCALE);
        f[6] = f2bf(b.z * SCALE); f[7] = f2bf(b.w * SCALE);
        qa[mt][kk] = f;
      }
  }
  // drain Q loads so manual vmcnt bookkeeping starts from zero outstanding
  asm volatile("s_waitcnt vmcnt(0)" ::: "memory");

  f32x4 acc[MT][8];
  #pragma unroll
  for (int mt = 0; mt < MT; mt++)
    #pragma unroll
    for (int dt = 0; dt < 8; dt++)
      acc[mt][dt] = (f32x4){0.f, 0.f, 0.f, 0.f};

  float lacc[MT] = {0.f, 0.f, 0.f, 0.f};

  const char* kbh = (const char*)(Kb + (size_t)bh * Ss * Dd);   // [s][d] bytes
  const char* vbh = (const char*)(Vt + (size_t)bh * Ss * Dd);   // [d][s] bytes

  // per-lane address components (bytes)
  // K: body (p,par), frag kk: row = 32p + 8*(l16>>2) + 4*par + (l16&3),
  //    col-chunk = kk*32 + quad*8  ->  klane + p*8192 + par*1024 + kk*64
  const unsigned klane = (unsigned)((8 * (l16 >> 2) + (l16 & 3)) * 256 + quad * 16);
  // V: pair p, instr i: src row d = i*16 + (lane>>2), key-chunk (lane&3)*8
  //    vlane + p*64 + i*(16*Ss*2)
  const unsigned vlane = (unsigned)((lane >> 2) * (Ss * 2) + (lane & 3) * 16);
  const unsigned ldst16 = (unsigned)(lane * 16);

  // ---- staging helpers ----
  auto stageK = [&](int p, int par, char* kb) {
    const unsigned base = klane + (unsigned)p * 8192u + (unsigned)par * 1024u;
    #pragma unroll
    for (int kk = 0; kk < 4; kk++)
      gload_lds16(kbh + base + kk * 64, kb + kk * 1024 + ldst16);
  };
  auto stageV = [&](int p) {
    const unsigned base = vlane + (unsigned)p * 64u;
    #pragma unroll
    for (int i = 0; i < 8; i++)
      gload_lds16(vbh + base + (unsigned)i * (16u * Ss * 2u), VB + i * 1024 + ldst16);
  };

  // ---- prologue: K(pair0,par0) -> KB0; V(pair0) -> VB  [12 outstanding] ----
  stageK(0, 0, KB0);
  stageV(0);

  for (int p = 0; p < NPAIR; p++) {
    unsigned pe[MT][2], po[MT][2];

    // ================= even body (par 0) =================
    // issue K(p, par1) -> KB1 ; for p>0 V(p) was issued at this body's top:
    stageK(p, 1, KB1);
    if (p > 0) stageV(p);            // safe: pair p-1's V reads ended last body
    // wait: drain K(p,par0) (oldest); leaves K(p,par1)+V(p) = 12
    asm volatile("s_waitcnt vmcnt(12)" ::: "memory");

    {
      f32x4 sc[MT];
      #pragma unroll
      for (int mt = 0; mt < MT; mt++) sc[mt] = (f32x4){0.f, 0.f, 0.f, 0.f};
      __builtin_amdgcn_s_setprio(1);
      #pragma unroll
      for (int kk = 0; kk < 4; kk++) {
        bf16x8 bk = *(const bf16x8*)(KB0 + kk * 1024 + ldst16);
        #pragma unroll
        for (int mt = 0; mt < MT; mt++)
          sc[mt] = __builtin_amdgcn_mfma_f32_16x16x32_bf16(bk, qa[mt][kk], sc[mt], 0, 0, 0);
      }
      __builtin_amdgcn_s_setprio(0);
      #pragma unroll
      for (int mt = 0; mt < MT; mt++) {
        float p0 = exp2_hw(sc[mt][0]);
        float p1 = exp2_hw(sc[mt][1]);
        float p2 = exp2_hw(sc[mt][2]);
        float p3 = exp2_hw(sc[mt][3]);
        lacc[mt] += (p0 + p1) + (p2 + p3);
        pe[mt][0] = pk2(p0, p1);
        pe[mt][1] = pk2(p2, p3);
      }
    }

    // ================= odd body (par 1) =================
    if (p < NPAIR - 1) {
      stageK(p + 1, 0, KB0);         // safe: KB0 reads (even body) already done
      asm volatile("s_waitcnt vmcnt(12)" ::: "memory");  // drain K(p,par1)
    } else {
      asm volatile("s_waitcnt vmcnt(8)" ::: "memory");   // drain K(p,par1)
    }

    {
      f32x4 sc[MT];
      #pragma unroll
      for (int mt = 0; mt < MT; mt++) sc[mt] = (f32x4){0.f, 0.f, 0.f, 0.f};
      __builtin_amdgcn_s_setprio(1);
      #pragma unroll
      for (int kk = 0; kk < 4; kk++) {
        bf16x8 bk = *(const bf16x8*)(KB1 + kk * 1024 + ldst16);
        #pragma unroll
        for (int mt = 0; mt < MT; mt++)
          sc[mt] = __builtin_amdgcn_mfma_f32_16x16x32_bf16(bk, qa[mt][kk], sc[mt], 0, 0, 0);
      }
      __builtin_amdgcn_s_setprio(0);
      #pragma unroll
      for (int mt = 0; mt < MT; mt++) {
        float p0 = exp2_hw(sc[mt][0]);
        float p1 = exp2_hw(sc[mt][1]);
        float p2 = exp2_hw(sc[mt][2]);
        float p3 = exp2_hw(sc[mt][3]);
        lacc[mt] += (p0 + p1) + (p2 + p3);
        po[mt][0] = pk2(p0, p1);
        po[mt][1] = pk2(p2, p3);
      }
    }

    // ---- PV over the pair (K=32): A = pa (lane-local P), B = V^T frag ----
    if (p < NPAIR - 1) asm volatile("s_waitcnt vmcnt(4)" ::: "memory");  // V(p) landed
    else               asm volatile("s_waitcnt vmcnt(0)" ::: "memory");

    bf16x8 pa[MT];
    #pragma unroll
    for (int mt = 0; mt < MT; mt++) {
      uint4 u4 = make_uint4(pe[mt][0], pe[mt][1], po[mt][0], po[mt][1]);
      pa[mt] = __builtin_bit_cast(bf16x8, u4);
    }
    __builtin_amdgcn_s_setprio(1);
    #pragma unroll
    for (int dt = 0; dt < 8; dt++) {
      // V^T[d = dt*16 + l16][key chunk quad*8] : addr = d*64 + quad*16
      bf16x8 bv = *(const bf16x8*)(VB + dt * 1024 + l16 * 64 + quad * 16);
      #pragma unroll
      for (int mt = 0; mt < MT; mt++)
        acc[mt][dt] = __builtin_amdgcn_mfma_f32_16x16x32_bf16(pa[mt], bv, acc[mt][dt], 0, 0, 0);
    }
    __builtin_amdgcn_s_setprio(0);
  }

  // ---- final l reduction: sum quads, broadcast to C-layout rows ----
  float inv_l[MT][4];
  #pragma unroll
  for (int mt = 0; mt < MT; mt++) {
    float l = lacc[mt];
    l += __shfl_xor(l, 16);
    l += __shfl_xor(l, 32);
    #pragma unroll
    for (int r = 0; r < 4; r++) {
      float lr = __shfl(l, (lane & 48) | (quad * 4 + r));
      inv_l[mt][r] = 1.0f / lr;
    }
  }

  // ---- epilogue: O / l ----
  float* ob = O + ((size_t)bh * Ss + q0 + w * 64) * Dd;
  #pragma unroll
  for (int mt = 0; mt < MT; mt++)
    #pragma unroll
    for (int r = 0; r < 4; r++) {
      const float inv = inv_l[mt][r];
      const int row = mt * 16 + quad * 4 + r;
      #pragma unroll
      for (int dt = 0; dt < 8; dt++)
        ob[row * Dd + dt * 16 + l16] = acc[mt][dt][r] * inv;
    }
}

extern "C" void kernel_launch(void* const* d_in, const int* in_sizes, int n_in,
                              void* d_out, int out_size, void* d_ws, size_t ws_size,
                              hipStream_t stream) {
  const float* Q = (const float*)d_in[0];
  const float* K = (const float*)d_in[1];
  const float* V = (const float*)d_in[2];
  float* O = (float*)d_out;
  const size_t elems = (size_t)BH * Ss * Dd;   // 16,777,216
  __bf16* Kb = (__bf16*)d_ws;
  __bf16* Vt = Kb + elems;

  k_prep<<<4096, 256, 0, stream>>>(K, Kb, V, Vt);
  k_flash<<<dim3((Ss / BM) * BH), 256, 0, stream>>>(Q, Kb, Vt, O);
}

// Round 11
// 374.763 us; speedup vs baseline: 1.0264x; 1.0264x over previous
//
#include <hip/hip_runtime.h>
#include <stdint.h>

// ---------- types ----------
typedef __bf16 bf16x8 __attribute__((ext_vector_type(8)));
typedef __bf16 bf16x2 __attribute__((ext_vector_type(2)));
typedef float  f32x4  __attribute__((ext_vector_type(4)));
typedef unsigned short u16x4 __attribute__((ext_vector_type(4)));
typedef unsigned short u16x8 __attribute__((ext_vector_type(8)));

#define DEVI __device__ __forceinline__

// problem constants
constexpr int Bc = 4, Hc = 16, Ss = 2048, Dd = 128;
constexpr int BH = Bc * Hc;          // 64 heads
constexpr int BM = 256;              // q-rows per workgroup (4 waves x 64), mt=4
constexpr int MT = 4;                // 16-row fragments per wave
constexpr int BN = 32;               // keys per K-tile
constexpr int NTIL = Ss / BN;        // 64 tiles
// scale folds in log2(e): e^(qk/128) = 2^((qk*log2e)/128)
constexpr float SCALE = 1.44269504088896340736f / 128.0f;

constexpr int TILE_B = BN * Dd * 2;  // 8192 B (one K tile; V tile same)
constexpr int SET_B  = 2 * TILE_B;   // 16384 B per buffer set {K, V}
constexpr int NSET   = 3;            // triple-buffer
constexpr int LDS_BYTES = NSET * SET_B;   // 49152 B -> 2 WGs/CU (grid = 2/CU exact)

DEVI unsigned short f2bf_bits(float x) {
  unsigned u = __builtin_bit_cast(unsigned, x);
  u += 0x7fffu + ((u >> 16) & 1u);          // round-to-nearest-even
  return (unsigned short)(u >> 16);
}
DEVI __bf16 f2bf(float x) {
  unsigned short b = f2bf_bits(x);
  return __builtin_bit_cast(__bf16, b);
}
// pack two fp32 -> dword of 2 bf16 (compiler emits v_cvt_pk_bf16_f32)
DEVI unsigned pk2(float a, float b) {
  bf16x2 t; t[0] = (__bf16)a; t[1] = (__bf16)b;
  return __builtin_bit_cast(unsigned, t);
}
// hardware 2^x (v_exp_f32)
DEVI float exp2_hw(float x) { return __builtin_amdgcn_exp2f(x); }

// async global->LDS, 16B per lane; LDS dest = wave-uniform base + lane*16
DEVI void gload_lds16(const void* g, void* l) {
  __builtin_amdgcn_global_load_lds(
      (const __attribute__((address_space(1))) unsigned*)(uintptr_t)g,
      (__attribute__((address_space(3))) unsigned*)(unsigned)(uintptr_t)l,
      16, 0, 0);
}

// ---------------- fused pre-pass (unchanged, measured-good) ----------------
constexpr int LDT2 = 136;
__global__ void k_prep(const float* __restrict__ kin, __bf16* __restrict__ kout,
                       const float* __restrict__ v, __bf16* __restrict__ vt) {
  __shared__ __align__(16) unsigned short tile[64 * LDT2];
  const int bx = blockIdx.x;
  const int u = threadIdx.x;
  if (bx >= 2048) {
    constexpr int N4 = (BH * Ss * Dd) / 4;
    int i = (bx - 2048) * 256 + u;
    const int stride = 2048 * 256;
    #pragma unroll
    for (int it = 0; it < N4 / (2048 * 256); it++, i += stride) {
      float4 x = ((const float4*)kin)[i];
      ushort4 o;
      o.x = f2bf_bits(x.x); o.y = f2bf_bits(x.y);
      o.z = f2bf_bits(x.z); o.w = f2bf_bits(x.w);
      ((ushort4*)kout)[i] = o;
    }
    return;
  }
  const int bh = bx >> 5;
  const int s0 = (bx & 31) * 64;
  const float4* src = (const float4*)(v + ((size_t)bh * Ss + s0) * Dd);
  #pragma unroll
  for (int i = 0; i < 8; i++) {
    int f = i * 256 + u;
    int row = f >> 5;
    int c4 = (f & 31) << 2;
    float4 x = src[f];
    u16x4 o;
    o[0] = f2bf_bits(x.x); o[1] = f2bf_bits(x.y);
    o[2] = f2bf_bits(x.z); o[3] = f2bf_bits(x.w);
    *(u16x4*)&tile[row * LDT2 + c4] = o;
  }
  __syncthreads();
  const int so = u & 7;
  const int dq = u >> 3;
  u16x4 tin[8];
  #pragma unroll
  for (int i = 0; i < 8; i++)
    tin[i] = *(const u16x4*)&tile[(so * 8 + i) * LDT2 + dq * 4];
  #pragma unroll
  for (int j = 0; j < 4; j++) {
    u16x8 o;
    #pragma unroll
    for (int i = 0; i < 8; i++) o[i] = tin[i][j];
    *(u16x8*)(vt + ((size_t)bh * Dd + dq * 4 + j) * Ss + s0 + so * 8) = o;
  }
}

// ---------------- flash attention: fine-phase schedule ----------------
// grid: 512 = 8 q-tiles x 64 heads. R9 staging (triple-buffer sets, counted
// vmcnt: loads span the whole tile, drain only t+1's 4 at tile end) + the
// T3-style fine phase split: per tile, three barrier-delimited phases
//   P1 {issue K-stage(t+2); bar; QKT-nt0 cluster; bar}
//   P2 {issue V-stage(t+2); bar; exp-nt0 (sm-split); QKT-nt1 cluster; bar}
//   P3 {exp-nt1; pack; PV cluster; vmcnt(4); bar}
// Phase barriers bound wave skew to ~one cluster so co-resident waves are in
// DIFFERENT sections (ds_read/exp vs MFMA) -> pipes overlap; setprio
// arbitrates for the MFMA wave (T5's role-split prerequisite now exists).
__launch_bounds__(256, 2)
__global__ void k_flash(const float* __restrict__ Q, const __bf16* __restrict__ Kb,
                        const __bf16* __restrict__ Vt, float* __restrict__ O) {
  __shared__ __align__(16) char lds[LDS_BYTES];

  const int tid = threadIdx.x;
  const int w = tid >> 6;           // wave 0..3, owns q-rows [64w, 64w+64)
  const int lane = tid & 63;
  const int quad = lane >> 4;
  const int l16 = lane & 15;

  const int bx = blockIdx.x;
  const int bh = bx & (BH - 1);
  const int q0 = (bx >> 6) * BM;

  // ---- Q fragments: fp32 load, scale, cvt to bf16, keep in regs ----
  bf16x8 qa[MT][4];
  {
    const float* qb = Q + ((size_t)bh * Ss + q0 + w * 64) * Dd;
    #pragma unroll
    for (int mt = 0; mt < MT; mt++)
      #pragma unroll
      for (int kk = 0; kk < 4; kk++) {
        const float* p = qb + (mt * 16 + l16) * Dd + kk * 32 + quad * 8;
        float4 a = ((const float4*)p)[0];
        float4 b = ((const float4*)p)[1];
        bf16x8 f;
        f[0] = f2bf(a.x * SCALE); f[1] = f2bf(a.y * SCALE);
        f[2] = f2bf(a.z * SCALE); f[3] = f2bf(a.w * SCALE);
        f[4] = f2bf(b.x * SCALE); f[5] = f2bf(b.y * SCALE);
        f[6] = f2bf(b.z * SCALE); f[7] = f2bf(b.w * SCALE);
        qa[mt][kk] = f;
      }
  }
  // drain Q loads so the manual vmcnt ledger starts from zero outstanding
  asm volatile("s_waitcnt vmcnt(0)" ::: "memory");

  f32x4 acc[MT][8];
  #pragma unroll
  for (int mt = 0; mt < MT; mt++)
    #pragma unroll
    for (int dt = 0; dt < 8; dt++)
      acc[mt][dt] = (f32x4){0.f, 0.f, 0.f, 0.f};

  float lacc[MT] = {0.f, 0.f, 0.f, 0.f};

  const __bf16* kbh = Kb + (size_t)bh * Ss * Dd;   // [s][d]
  const __bf16* vbh = Vt + (size_t)bh * Ss * Dd;   // [d][s]

  // ---- per-wave stage assignment: waves 0,1 -> K frags; waves 2,3 -> V frags ----
  const char* gp[4];
  unsigned lo[4];
  int ginc;
  const bool isK = (w < 2);
  if (isK) {
    // K frag (kk,nt): LDS row l16 holds actual key 8*(l16>>2) + 4*nt + (l16&3)
    #pragma unroll
    for (int i = 0; i < 4; i++) {
      const int fk = w * 4 + i, kk = fk >> 1, nt = fk & 1;
      const int key = 8 * (l16 >> 2) + 4 * nt + (l16 & 3);
      gp[i] = (const char*)(kbh + (size_t)key * Dd + kk * 32 + quad * 8);
      lo[i] = (unsigned)(fk * 1024 + lane * 16);
    }
    ginc = BN * Dd * 2;             // next K tile: +32 keys
  } else {
    #pragma unroll
    for (int i = 0; i < 4; i++) {
      const int dt = (w - 2) * 4 + i;
      gp[i] = (const char*)(vbh + (size_t)(dt * 16 + l16) * Ss + quad * 8);
      lo[i] = (unsigned)(TILE_B + dt * 1024 + lane * 16);
    }
    ginc = BN * 2;                  // next V tile: +32 columns
  }

  // ---- prologue: stage tile 0 -> set 0, tile 1 -> set 1 ----
  #pragma unroll
  for (int i = 0; i < 4; i++) { gload_lds16(gp[i], lds + lo[i]); gp[i] += ginc; }
  #pragma unroll
  for (int i = 0; i < 4; i++) { gload_lds16(gp[i], lds + lo[i] + SET_B); gp[i] += ginc; }
  asm volatile("s_waitcnt vmcnt(4)" ::: "memory");   // tile 0 landed; tile 1 in flight
  __builtin_amdgcn_s_barrier();

  unsigned cbase = 0;               // compute set base
  for (int t = 0; t < NTIL; t++) {
    unsigned sbase = cbase + 2 * SET_B;
    if (sbase >= (unsigned)LDS_BYTES) sbase -= (unsigned)LDS_BYTES;
    const char* bK = lds + cbase;
    const char* bV = lds + cbase + TILE_B;
    const bool doStage = (t < NTIL - 2);

    // =========== P1: issue K-stage(t+2); QKT-nt0 cluster ===========
    if (isK && doStage) {
      #pragma unroll
      for (int i = 0; i < 4; i++) { gload_lds16(gp[i], lds + lo[i] + sbase); gp[i] += ginc; }
    }
    __builtin_amdgcn_s_barrier();
    f32x4 sc0[MT];
    #pragma unroll
    for (int mt = 0; mt < MT; mt++) sc0[mt] = (f32x4){0.f, 0.f, 0.f, 0.f};
    __builtin_amdgcn_s_setprio(1);
    #pragma unroll
    for (int kk = 0; kk < 4; kk++) {
      bf16x8 bk = *(const bf16x8*)(bK + (kk * 2 + 0) * 1024 + lane * 16);
      #pragma unroll
      for (int mt = 0; mt < MT; mt++)
        sc0[mt] = __builtin_amdgcn_mfma_f32_16x16x32_bf16(bk, qa[mt][kk], sc0[mt], 0, 0, 0);
    }
    __builtin_amdgcn_s_setprio(0);
    __builtin_amdgcn_s_barrier();

    // =========== P2: issue V-stage(t+2); exp-nt0 (sm-split); QKT-nt1 ===========
    if (!isK && doStage) {
      #pragma unroll
      for (int i = 0; i < 4; i++) { gload_lds16(gp[i], lds + lo[i] + sbase); gp[i] += ginc; }
    }
    __builtin_amdgcn_s_barrier();
    unsigned pp[MT][4];
    #pragma unroll
    for (int mt = 0; mt < MT; mt++) {
      float p0 = exp2_hw(sc0[mt][0]);
      float p1 = exp2_hw(sc0[mt][1]);
      float p2 = exp2_hw(sc0[mt][2]);
      float p3 = exp2_hw(sc0[mt][3]);
      lacc[mt] += (p0 + p1) + (p2 + p3);
      pp[mt][0] = pk2(p0, p1);
      pp[mt][1] = pk2(p2, p3);
    }
    f32x4 sc1[MT];
    #pragma unroll
    for (int mt = 0; mt < MT; mt++) sc1[mt] = (f32x4){0.f, 0.f, 0.f, 0.f};
    __builtin_amdgcn_s_setprio(1);
    #pragma unroll
    for (int kk = 0; kk < 4; kk++) {
      bf16x8 bk = *(const bf16x8*)(bK + (kk * 2 + 1) * 1024 + lane * 16);
      #pragma unroll
      for (int mt = 0; mt < MT; mt++)
        sc1[mt] = __builtin_amdgcn_mfma_f32_16x16x32_bf16(bk, qa[mt][kk], sc1[mt], 0, 0, 0);
    }
    __builtin_amdgcn_s_setprio(0);
    __builtin_amdgcn_s_barrier();

    // =========== P3: exp-nt1; pack; PV cluster; counted drain ===========
    #pragma unroll
    for (int mt = 0; mt < MT; mt++) {
      float p0 = exp2_hw(sc1[mt][0]);
      float p1 = exp2_hw(sc1[mt][1]);
      float p2 = exp2_hw(sc1[mt][2]);
      float p3 = exp2_hw(sc1[mt][3]);
      lacc[mt] += (p0 + p1) + (p2 + p3);
      pp[mt][2] = pk2(p0, p1);
      pp[mt][3] = pk2(p2, p3);
    }
    bf16x8 pa[MT];
    #pragma unroll
    for (int mt = 0; mt < MT; mt++) {
      uint4 u4 = make_uint4(pp[mt][0], pp[mt][1], pp[mt][2], pp[mt][3]);
      pa[mt] = __builtin_bit_cast(bf16x8, u4);
    }
    __builtin_amdgcn_s_setprio(1);
    #pragma unroll
    for (int dt = 0; dt < 8; dt++) {
      bf16x8 bv = *(const bf16x8*)(bV + dt * 1024 + lane * 16);
      #pragma unroll
      for (int mt = 0; mt < MT; mt++)
        acc[mt][dt] = __builtin_amdgcn_mfma_f32_16x16x32_bf16(pa[mt], bv, acc[mt][dt], 0, 0, 0);
    }
    __builtin_amdgcn_s_setprio(0);

    if (t < NTIL - 1) {
      if (t < NTIL - 2) asm volatile("s_waitcnt vmcnt(4)" ::: "memory");
      else              asm volatile("s_waitcnt vmcnt(0)" ::: "memory");
      __builtin_amdgcn_s_barrier();
    }
    cbase += SET_B;
    if (cbase >= (unsigned)LDS_BYTES) cbase = 0;
  }

  // ---- final l reduction: sum quads, broadcast to C-layout rows ----
  float inv_l[MT][4];
  #pragma unroll
  for (int mt = 0; mt < MT; mt++) {
    float l = lacc[mt];
    l += __shfl_xor(l, 16);
    l += __shfl_xor(l, 32);
    #pragma unroll
    for (int r = 0; r < 4; r++) {
      float lr = __shfl(l, (lane & 48) | (quad * 4 + r));
      inv_l[mt][r] = 1.0f / lr;
    }
  }

  // ---- epilogue: O / l ----
  float* ob = O + ((size_t)bh * Ss + q0 + w * 64) * Dd;
  #pragma unroll
  for (int mt = 0; mt < MT; mt++)
    #pragma unroll
    for (int r = 0; r < 4; r++) {
      const float inv = inv_l[mt][r];
      const int row = mt * 16 + quad * 4 + r;
      #pragma unroll
      for (int dt = 0; dt < 8; dt++)
        ob[row * Dd + dt * 16 + l16] = acc[mt][dt][r] * inv;
    }
}

extern "C" void kernel_launch(void* const* d_in, const int* in_sizes, int n_in,
                              void* d_out, int out_size, void* d_ws, size_t ws_size,
                              hipStream_t stream) {
  const float* Q = (const float*)d_in[0];
  const float* K = (const float*)d_in[1];
  const float* V = (const float*)d_in[2];
  float* O = (float*)d_out;
  const size_t elems = (size_t)BH * Ss * Dd;   // 16,777,216
  __bf16* Kb = (__bf16*)d_ws;
  __bf16* Vt = Kb + elems;

  k_prep<<<4096, 256, 0, stream>>>(K, Kb, V, Vt);
  k_flash<<<dim3((Ss / BM) * BH), 256, 0, stream>>>(Q, Kb, Vt, O);
}

// Round 12
// 366.814 us; speedup vs baseline: 1.0486x; 1.0217x over previous
//
#include <hip/hip_runtime.h>
#include <stdint.h>

// ---------- types ----------
typedef __bf16 bf16x8 __attribute__((ext_vector_type(8)));
typedef __bf16 bf16x2 __attribute__((ext_vector_type(2)));
typedef float  f32x16 __attribute__((ext_vector_type(16)));
typedef unsigned short u16x4 __attribute__((ext_vector_type(4)));
typedef unsigned short u16x8 __attribute__((ext_vector_type(8)));

#define DEVI __device__ __forceinline__

// problem constants
constexpr int Bc = 4, Hc = 16, Ss = 2048, Dd = 128;
constexpr int BH = Bc * Hc;          // 64 heads
constexpr int BM = 256;              // q-rows per workgroup (4 waves x 64)
constexpr int BN = 32;               // keys per tile (double-buffered)
constexpr int NTIL = Ss / BN;        // 64 tiles
// scale folds in log2(e): e^(qk/128) = 2^((qk*log2e)/128)
constexpr float SCALE = 1.44269504088896340736f / 128.0f;

constexpr int TILE_B = BN * Dd * 2;  // 8192 B
constexpr int SK_OFF = 0;            // 2 buffers x 8 KiB (K tiles, pi-permuted rows)
constexpr int SV_OFF = 2 * TILE_B;   // 2 buffers x 8 KiB (V^T fragment tiles)
constexpr int LDS_BYTES = 4 * TILE_B;   // 32768 B

DEVI unsigned short f2bf_bits(float x) {
  unsigned u = __builtin_bit_cast(unsigned, x);
  u += 0x7fffu + ((u >> 16) & 1u);          // round-to-nearest-even
  return (unsigned short)(u >> 16);
}
DEVI __bf16 f2bf(float x) {
  unsigned short b = f2bf_bits(x);
  return __builtin_bit_cast(__bf16, b);
}
// pack two fp32 -> dword of 2 bf16 (compiler emits v_cvt_pk_bf16_f32)
DEVI unsigned pk2(float a, float b) {
  bf16x2 t; t[0] = (__bf16)a; t[1] = (__bf16)b;
  return __builtin_bit_cast(unsigned, t);
}
// hardware 2^x (v_exp_f32)
DEVI float exp2_hw(float x) { return __builtin_amdgcn_exp2f(x); }

// async global->LDS, 16B per lane; LDS dest = wave-uniform base + lane*16
DEVI void gload_lds16(const void* g, void* l) {
  __builtin_amdgcn_global_load_lds(
      (const __attribute__((address_space(1))) unsigned*)(uintptr_t)g,
      (__attribute__((address_space(3))) unsigned*)(unsigned)(uintptr_t)l,
      16, 0, 0);
}

// ---------------- fused pre-pass (unchanged, measured-good) ----------------
constexpr int LDT2 = 136;
__global__ void k_prep(const float* __restrict__ kin, __bf16* __restrict__ kout,
                       const float* __restrict__ v, __bf16* __restrict__ vt) {
  __shared__ __align__(16) unsigned short tile[64 * LDT2];
  const int bx = blockIdx.x;
  const int u = threadIdx.x;
  if (bx >= 2048) {
    constexpr int N4 = (BH * Ss * Dd) / 4;
    int i = (bx - 2048) * 256 + u;
    const int stride = 2048 * 256;
    #pragma unroll
    for (int it = 0; it < N4 / (2048 * 256); it++, i += stride) {
      float4 x = ((const float4*)kin)[i];
      ushort4 o;
      o.x = f2bf_bits(x.x); o.y = f2bf_bits(x.y);
      o.z = f2bf_bits(x.z); o.w = f2bf_bits(x.w);
      ((ushort4*)kout)[i] = o;
    }
    return;
  }
  const int bh = bx >> 5;
  const int s0 = (bx & 31) * 64;
  const float4* src = (const float4*)(v + ((size_t)bh * Ss + s0) * Dd);
  #pragma unroll
  for (int i = 0; i < 8; i++) {
    int f = i * 256 + u;
    int row = f >> 5;
    int c4 = (f & 31) << 2;
    float4 x = src[f];
    u16x4 o;
    o[0] = f2bf_bits(x.x); o[1] = f2bf_bits(x.y);
    o[2] = f2bf_bits(x.z); o[3] = f2bf_bits(x.w);
    *(u16x4*)&tile[row * LDT2 + c4] = o;
  }
  __syncthreads();
  const int so = u & 7;
  const int dq = u >> 3;
  u16x4 tin[8];
  #pragma unroll
  for (int i = 0; i < 8; i++)
    tin[i] = *(const u16x4*)&tile[(so * 8 + i) * LDT2 + dq * 4];
  #pragma unroll
  for (int j = 0; j < 4; j++) {
    u16x8 o;
    #pragma unroll
    for (int i = 0; i < 8; i++) o[i] = tin[i][j];
    *(u16x8*)(vt + ((size_t)bh * Dd + dq * 4 + j) * Ss + s0 + so * 8) = o;
  }
}

// ---------------- flash attention: 32x32x16 MFMA ----------------
// grid: 512 = 8 q-tiles x 64 heads. R5 pipeline (2-buffer, stage-then-compute,
// one barrier/tile), but 32 MFMA/wave-body of 32x32x16 instead of 64 of
// 16x16x32: halves MFMA instruction count (issue/wave-block overhead), -13%
// matrix-pipe cycles. In-register softmax preserved: K rows staged with
// pi(s) = s^12 for (s>>2)&3 in {1,2}, which makes S^T C-layout regs r=0..15
// hold keys 16*(r>>3) + 8*hi + (r&7) -- i.e. exp'd scores in exactly the
// j-order the PV A-fragment (32x32x16 A: row=lane&31=q, k=8*hi+j) needs.
__launch_bounds__(256, 2)
__global__ void k_flash(const float* __restrict__ Q, const __bf16* __restrict__ Kb,
                        const __bf16* __restrict__ Vt, float* __restrict__ O) {
  __shared__ __align__(16) char lds[LDS_BYTES];

  const int tid = threadIdx.x;
  const int w = tid >> 6;           // wave 0..3, owns q-rows [64w, 64w+64)
  const int lane = tid & 63;
  const int l32 = lane & 31;
  const int hi = lane >> 5;

  const int bx = blockIdx.x;
  const int bh = bx & (BH - 1);
  const int q0 = (bx >> 6) * BM;

  // ---- Q fragments (B-operand): lane holds Q[qb*32+l32][kk*16+8*hi+j] ----
  bf16x8 qa[2][8];
  {
    const float* qb = Q + ((size_t)bh * Ss + q0 + w * 64) * Dd;
    #pragma unroll
    for (int q = 0; q < 2; q++)
      #pragma unroll
      for (int kk = 0; kk < 8; kk++) {
        const float* p = qb + (q * 32 + l32) * Dd + kk * 16 + hi * 8;
        float4 a = ((const float4*)p)[0];
        float4 b = ((const float4*)p)[1];
        bf16x8 f;
        f[0] = f2bf(a.x * SCALE); f[1] = f2bf(a.y * SCALE);
        f[2] = f2bf(a.z * SCALE); f[3] = f2bf(a.w * SCALE);
        f[4] = f2bf(b.x * SCALE); f[5] = f2bf(b.y * SCALE);
        f[6] = f2bf(b.z * SCALE); f[7] = f2bf(b.w * SCALE);
        qa[q][kk] = f;
      }
  }

  f32x16 acc[2][4];                  // 128 VGPR: [qb][db], D[q][d] 32x32 tiles
  #pragma unroll
  for (int q = 0; q < 2; q++)
    #pragma unroll
    for (int db = 0; db < 4; db++)
      #pragma unroll
      for (int e = 0; e < 16; e++)
        acc[q][db][e] = 0.f;

  float lacc[2] = {0.f, 0.f};        // per-lane: q = qb*32 + l32 (constant/lane)

  const char* kbh = (const char*)(Kb + (size_t)bh * Ss * Dd);   // [s][d], 256 B/row
  const char* vbh = (const char*)(Vt + (size_t)bh * Ss * Dd);   // [d][s], 4096 B/row

  // ---- per-wave stage assignment: 16 frags (8 K + 8 V), 4 per wave ----
  // K frag kk: A-layout row sigma=l32 <- key pi(sigma), d-chunk kk*16+8*hi.
  // V frag f=(s,db): B-layout col d=db*32+l32, keys s*16+8*hi..+7.
  const char* gp[4];
  unsigned lo[4];
  int ginc;
  {
    const int b2 = (l32 >> 2) & 3;
    const int key = (b2 == 1 || b2 == 2) ? (l32 ^ 12) : l32;   // pi
    if (w < 2) {
      #pragma unroll
      for (int i = 0; i < 4; i++) {
        const int kk = w * 4 + i;
        gp[i] = kbh + (size_t)key * 256 + kk * 32 + hi * 16;
        lo[i] = (unsigned)(SK_OFF + kk * 1024 + lane * 16);
      }
      ginc = BN * 256;               // next K tile: +32 keys
    } else {
      #pragma unroll
      for (int i = 0; i < 4; i++) {
        const int f = (w - 2) * 4 + i, s = f >> 2, db = f & 3;
        gp[i] = vbh + (size_t)(db * 32 + l32) * (Ss * 2) + (s * 16 + hi * 8) * 2;
        lo[i] = (unsigned)(SV_OFF + f * 1024 + lane * 16);
      }
      ginc = BN * 2;                 // next V tile: +32 key-columns
    }
  }

  // ---- prologue: stage tile 0 into buffer 0 ----
  #pragma unroll
  for (int i = 0; i < 4; i++) gload_lds16(gp[i], lds + lo[i]);
  #pragma unroll
  for (int i = 0; i < 4; i++) gp[i] += ginc;
  __syncthreads();

  unsigned cur = 0;
  for (int t = 0; t < NTIL; t++) {
    // ---- issue next-tile stage FIRST (into the other buffer) ----
    if (t < NTIL - 1) {
      const unsigned nb = (cur ^ 1u) * (unsigned)TILE_B;
      #pragma unroll
      for (int i = 0; i < 4; i++) gload_lds16(gp[i], lds + lo[i] + nb);
      #pragma unroll
      for (int i = 0; i < 4; i++) gp[i] += ginc;
    }
    const char* bK = lds + SK_OFF + cur * TILE_B;
    const char* bV = lds + SV_OFF + cur * TILE_B;

    // ---- S^T = K Q^T: 16 MFMA of 32x32x16 (8 kk x 2 qb) ----
    f32x16 sc0, sc1;
    #pragma unroll
    for (int e = 0; e < 16; e++) { sc0[e] = 0.f; sc1[e] = 0.f; }
    __builtin_amdgcn_s_setprio(1);
    #pragma unroll
    for (int kk = 0; kk < 8; kk++) {
      bf16x8 bk = *(const bf16x8*)(bK + kk * 1024 + lane * 16);
      sc0 = __builtin_amdgcn_mfma_f32_32x32x16_bf16(bk, qa[0][kk], sc0, 0, 0, 0);
      sc1 = __builtin_amdgcn_mfma_f32_32x32x16_bf16(bk, qa[1][kk], sc1, 0, 0, 0);
    }
    __builtin_amdgcn_s_setprio(0);

    // ---- exp2 + accumulate l + pack to PV A-fragments (in registers) ----
    // sc reg r holds key 16*(r>>3) + 8*hi + (r&7) for q = qb*32 + l32.
    float e0[16], e1[16];
    #pragma unroll
    for (int r = 0; r < 16; r++) {
      e0[r] = exp2_hw(sc0[r]);
      e1[r] = exp2_hw(sc1[r]);
    }
    #pragma unroll
    for (int r = 0; r < 8; r++) { lacc[0] += e0[r] + e0[r + 8]; lacc[1] += e1[r] + e1[r + 8]; }
    bf16x8 pa0[2], pa1[2];           // [k-step s]: elems j=0..7 = keys 16s+8hi+j
    #pragma unroll
    for (int s = 0; s < 2; s++) {
      uint4 u0, u1;
      u0.x = pk2(e0[s * 8 + 0], e0[s * 8 + 1]); u0.y = pk2(e0[s * 8 + 2], e0[s * 8 + 3]);
      u0.z = pk2(e0[s * 8 + 4], e0[s * 8 + 5]); u0.w = pk2(e0[s * 8 + 6], e0[s * 8 + 7]);
      u1.x = pk2(e1[s * 8 + 0], e1[s * 8 + 1]); u1.y = pk2(e1[s * 8 + 2], e1[s * 8 + 3]);
      u1.z = pk2(e1[s * 8 + 4], e1[s * 8 + 5]); u1.w = pk2(e1[s * 8 + 6], e1[s * 8 + 7]);
      pa0[s] = __builtin_bit_cast(bf16x8, u0);
      pa1[s] = __builtin_bit_cast(bf16x8, u1);
    }

    // ---- O += P V: 16 MFMA of 32x32x16 (2 s x 4 db x 2 qb) ----
    __builtin_amdgcn_s_setprio(1);
    #pragma unroll
    for (int s = 0; s < 2; s++)
      #pragma unroll
      for (int db = 0; db < 4; db++) {
        bf16x8 bv = *(const bf16x8*)(bV + (s * 4 + db) * 1024 + lane * 16);
        acc[0][db] = __builtin_amdgcn_mfma_f32_32x32x16_bf16(pa0[s], bv, acc[0][db], 0, 0, 0);
        acc[1][db] = __builtin_amdgcn_mfma_f32_32x32x16_bf16(pa1[s], bv, acc[1][db], 0, 0, 0);
      }
    __builtin_amdgcn_s_setprio(0);

    __syncthreads();    // waves done reading buf `cur`; stage of buf^1 drained here
    cur ^= 1u;
  }

  // ---- final l: lane holds partial for q=qb*32+l32 over its hi-half keys ----
  float Lf[2];
  #pragma unroll
  for (int q = 0; q < 2; q++) {
    float l = lacc[q];
    l += __shfl_xor(l, 32);          // add complementary half -> full denominator
    Lf[q] = l;
  }

  // ---- epilogue: O[q][d] = acc * (1/L(q)); C-layout row=(r&3)+8*(r>>2)+4*hi ----
  float* ob = O + ((size_t)bh * Ss + q0 + w * 64) * Dd;
  #pragma unroll
  for (int q = 0; q < 2; q++)
    #pragma unroll
    for (int r = 0; r < 16; r++) {
      const int qrow = (r & 3) + 8 * (r >> 2) + 4 * hi;       // 0..31 within qb
      const float inv = 1.0f / __shfl(Lf[q], qrow);           // lane qrow holds L(qrow)
      #pragma unroll
      for (int db = 0; db < 4; db++)
        ob[(q * 32 + qrow) * Dd + db * 32 + l32] = acc[q][db][r] * inv;
    }
}

extern "C" void kernel_launch(void* const* d_in, const int* in_sizes, int n_in,
                              void* d_out, int out_size, void* d_ws, size_t ws_size,
                              hipStream_t stream) {
  const float* Q = (const float*)d_in[0];
  const float* K = (const float*)d_in[1];
  const float* V = (const float*)d_in[2];
  float* O = (float*)d_out;
  const size_t elems = (size_t)BH * Ss * Dd;   // 16,777,216
  __bf16* Kb = (__bf16*)d_ws;
  __bf16* Vt = Kb + elems;

  k_prep<<<4096, 256, 0, stream>>>(K, Kb, V, Vt);
  k_flash<<<dim3((Ss / BM) * BH), 256, 0, stream>>>(Q, Kb, Vt, O);
}